// Round 16
// baseline (245.301 us; speedup 1.0000x reference)
//
#include <hip/hip_runtime.h>

typedef __bf16 bf16;
typedef __bf16 bf16x8 __attribute__((ext_vector_type(8)));
typedef float f32x4 __attribute__((ext_vector_type(4)));
typedef float f32x16 __attribute__((ext_vector_type(16)));
typedef unsigned int uint;
typedef uint uint2v __attribute__((ext_vector_type(2)));

#define GLOAD16(g, l)                                                        \
  __builtin_amdgcn_global_load_lds(                                          \
      (const __attribute__((address_space(1))) void*)(g),                    \
      (__attribute__((address_space(3))) void*)(l), 16, 0, 0)

__device__ inline uint pack_bf16(float a, float b) {
  union { bf16 h[2]; uint u; } x;
  x.h[0] = (bf16)a; x.h[1] = (bf16)b;
  return x.u;
}

// ---------------- casts ----------------
__global__ void cast_f32_to_bf16(const float* __restrict__ in,
                                 bf16* __restrict__ out, int n8, float scale) {
  int i = blockIdx.x * blockDim.x + threadIdx.x;
  if (i >= n8) return;
  const float4* p = reinterpret_cast<const float4*>(in) + (size_t)i * 2;
  float4 a = p[0], b = p[1];
  bf16x8 o;
  o[0] = (bf16)(a.x * scale); o[1] = (bf16)(a.y * scale);
  o[2] = (bf16)(a.z * scale); o[3] = (bf16)(a.w * scale);
  o[4] = (bf16)(b.x * scale); o[5] = (bf16)(b.y * scale);
  o[6] = (bf16)(b.z * scale); o[7] = (bf16)(b.w * scale);
  *reinterpret_cast<bf16x8*>(out + (size_t)i * 8) = o;
}

__global__ void cast4(const float* __restrict__ x, const float* __restrict__ wq,
                      const float* __restrict__ wk, const float* __restrict__ wv,
                      bf16* __restrict__ xb, bf16* __restrict__ wqk,
                      bf16* __restrict__ wvb, float qscale) {
  int i = blockIdx.x * blockDim.x + threadIdx.x;
  const float* src;
  bf16* dst;
  float s = 1.0f;
  int j;
  if (i < 1048576) {
    src = x; dst = xb; j = i;
  } else {
    int k = i - 1048576;
    int r = k >> 19;
    j = k & 524287;
    src = r == 0 ? wq : r == 1 ? wk : wv;
    dst = r == 0 ? wqk : r == 1 ? wqk + 4194304 : wvb;
    s = r == 0 ? qscale : 1.0f;
  }
  const float4* p = reinterpret_cast<const float4*>(src) + (size_t)j * 2;
  float4 a = p[0], b = p[1];
  bf16x8 o;
  o[0] = (bf16)(a.x * s); o[1] = (bf16)(a.y * s);
  o[2] = (bf16)(a.z * s); o[3] = (bf16)(a.w * s);
  o[4] = (bf16)(b.x * s); o[5] = (bf16)(b.y * s);
  o[6] = (bf16)(b.z * s); o[7] = (bf16)(b.w * s);
  *reinterpret_cast<bf16x8*>(dst + (size_t)j * 8) = o;
}

// ---------------- 256x256 deep-pipelined NT GEMM (QK projection) ------------
template <typename OT>
__global__ __launch_bounds__(512, 1) void gemm_nt_256sq(
    const bf16* __restrict__ A, const bf16* __restrict__ B, OT* __restrict__ C,
    int K, int lda, int ldb, int ldc, long cSplit) {
  extern __shared__ char sh[];
  const int t = threadIdx.x;
  const int w = t >> 6, lane = t & 63;
  const int l15 = lane & 15, l4 = lane >> 4;
  const int wr = w >> 2, wc = w & 3;
  const int gx = gridDim.x, gy = gridDim.y;
  const int nwg = gx * gy;
  const int bid = blockIdx.y * gx + blockIdx.x;
  const int fid = (bid & 7) * (nwg >> 3) + (bid >> 3);
  const int by = fid / gx, bx = fid - by * gx;
  const int m0 = by * 256, n0 = bx * 256;
  OT* Cg = C + ((n0 & 2048) ? cSplit : 0);

  int sRow[4], sCol[4];
#pragma unroll
  for (int i = 0; i < 4; i++) {
    int sB_ = (i * 512 + t) * 16;
    int row = sB_ >> 7;
    int ge = (sB_ ^ ((row & 7) << 4)) >> 1;
    sRow[i] = ge >> 6;
    sCol[i] = ge & 63;
  }

  const int NT = K >> 6;
  f32x4 acc[8][4] = {};

  auto stage = [&](int tt) {
    char* dst = sh + (size_t)(tt & 1) * 65536;
    const int k0 = tt * 64;
#pragma unroll
    for (int i = 0; i < 4; i++)
      GLOAD16(A + (size_t)(m0 + sRow[i]) * lda + k0 + sCol[i],
              dst + (i * 512 + w * 64) * 16);
#pragma unroll
    for (int i = 0; i < 4; i++)
      GLOAD16(B + (size_t)(n0 + sRow[i]) * ldb + k0 + sCol[i],
              dst + 32768 + (i * 512 + w * 64) * 16);
  };

  stage(0);
  for (int tt = 0; tt < NT; ++tt) {
    asm volatile("s_waitcnt vmcnt(0)" ::: "memory");
    __builtin_amdgcn_s_barrier();

    const char* Ab = sh + (size_t)(tt & 1) * 65536;
    const char* Bb = Ab + 32768;
    bf16x8 bfr[4][2];
#pragma unroll
    for (int n = 0; n < 4; n++)
#pragma unroll
      for (int kk = 0; kk < 2; kk++) {
        int row = wc * 64 + n * 16 + l15;
        int off = (row * 128 + kk * 64 + l4 * 16) ^ ((row & 7) << 4);
        bfr[n][kk] = *reinterpret_cast<const bf16x8*>(Bb + off);
      }
#pragma unroll
    for (int mp = 0; mp < 4; mp++) {
      bf16x8 af[2][2];
#pragma unroll
      for (int m = 0; m < 2; m++)
#pragma unroll
        for (int kk = 0; kk < 2; kk++) {
          int row = wr * 128 + (mp * 2 + m) * 16 + l15;
          int off = (row * 128 + kk * 64 + l4 * 16) ^ ((row & 7) << 4);
          af[m][kk] = *reinterpret_cast<const bf16x8*>(Ab + off);
        }
      __builtin_amdgcn_s_setprio(1);
#pragma unroll
      for (int m = 0; m < 2; m++)
#pragma unroll
        for (int n = 0; n < 4; n++)
#pragma unroll
          for (int kk = 0; kk < 2; kk++)
            acc[mp * 2 + m][n] = __builtin_amdgcn_mfma_f32_16x16x32_bf16(
                af[m][kk], bfr[n][kk], acc[mp * 2 + m][n], 0, 0, 0);
      __builtin_amdgcn_s_setprio(0);
      if (mp == 0 && tt + 1 < NT) stage(tt + 1);
    }
  }

#pragma unroll
  for (int m = 0; m < 8; m++)
#pragma unroll
    for (int n = 0; n < 4; n++)
#pragma unroll
      for (int j = 0; j < 4; j++) {
        int row = m0 + wr * 128 + m * 16 + l4 * 4 + j;
        int col = n0 + wc * 64 + n * 16 + l15;
        Cg[(size_t)row * ldc + col] = (OT)acc[m][n][j];
      }
}

// ---------------- 256x128 deep-pipelined NT GEMM (V, O-proj) ----------------
template <typename OT>
__global__ __launch_bounds__(512, 2) void gemm_nt_256(
    const bf16* __restrict__ A, const bf16* __restrict__ B, OT* __restrict__ C,
    int K, int lda, int ldb, int ldc, long bsB, long bsC, long cSplit) {
  extern __shared__ char sh[];
  const int t = threadIdx.x;
  const int w = t >> 6, lane = t & 63;
  const int l15 = lane & 15, l4 = lane >> 4;
  const int wr = w >> 1, wc = w & 1;
  const int gx = gridDim.x, gy = gridDim.y;
  const int nwg = gx * gy;
  const int bid = blockIdx.y * gx + blockIdx.x;
  const int fid = (bid & 7) * (nwg >> 3) + (bid >> 3);
  const int by = fid / gx, bx = fid - by * gx;
  const int m0 = by * 256;
  const int n0 = bx * 128;
  const bf16* Bg = B + (size_t)blockIdx.z * bsB;
  OT* Cg = C + (size_t)blockIdx.z * bsC + ((n0 & 2048) ? cSplit : 0);

  int sRow[4], sCol[4];
#pragma unroll
  for (int i = 0; i < 4; i++) {
    int sB_ = (i * 512 + t) * 16;
    int row = sB_ >> 7;
    int ge = (sB_ ^ ((row & 7) << 4)) >> 1;
    sRow[i] = ge >> 6;
    sCol[i] = ge & 63;
  }

  const int NT = K >> 6;
  f32x4 acc[4][4] = {};

  auto stage = [&](int tt) {
    char* dst = sh + (size_t)(tt % 3) * 49152;
    const int k0 = tt * 64;
#pragma unroll
    for (int i = 0; i < 4; i++)
      GLOAD16(A + (size_t)(m0 + sRow[i]) * lda + k0 + sCol[i],
              dst + (i * 512 + w * 64) * 16);
#pragma unroll
    for (int i = 0; i < 2; i++)
      GLOAD16(Bg + (size_t)(n0 + sRow[i]) * ldb + k0 + sCol[i],
              dst + 32768 + (i * 512 + w * 64) * 16);
  };

  stage(0);
  stage(1);
  for (int tt = 0; tt < NT; ++tt) {
    if (tt < NT - 1)
      asm volatile("s_waitcnt vmcnt(6)" ::: "memory");
    else
      asm volatile("s_waitcnt vmcnt(0)" ::: "memory");
    __builtin_amdgcn_s_barrier();

    const char* Ab = sh + (size_t)(tt % 3) * 49152;
    const char* Bb = Ab + 32768;
    bf16x8 bfr[4][2];
#pragma unroll
    for (int n = 0; n < 4; n++)
#pragma unroll
      for (int kk = 0; kk < 2; kk++) {
        int row = wc * 64 + n * 16 + l15;
        int off = (row * 128 + kk * 64 + l4 * 16) ^ ((row & 7) << 4);
        bfr[n][kk] = *reinterpret_cast<const bf16x8*>(Bb + off);
      }
    bf16x8 af0[2][2];
#pragma unroll
    for (int m = 0; m < 2; m++)
#pragma unroll
      for (int kk = 0; kk < 2; kk++) {
        int row = wr * 64 + m * 16 + l15;
        int off = (row * 128 + kk * 64 + l4 * 16) ^ ((row & 7) << 4);
        af0[m][kk] = *reinterpret_cast<const bf16x8*>(Ab + off);
      }
    __builtin_amdgcn_s_setprio(1);
#pragma unroll
    for (int m = 0; m < 2; m++)
#pragma unroll
      for (int n = 0; n < 4; n++)
#pragma unroll
        for (int kk = 0; kk < 2; kk++)
          acc[m][n] = __builtin_amdgcn_mfma_f32_16x16x32_bf16(
              af0[m][kk], bfr[n][kk], acc[m][n], 0, 0, 0);
    __builtin_amdgcn_s_setprio(0);

    if (tt + 2 < NT) stage(tt + 2);

    bf16x8 af1[2][2];
#pragma unroll
    for (int m = 0; m < 2; m++)
#pragma unroll
      for (int kk = 0; kk < 2; kk++) {
        int row = wr * 64 + (2 + m) * 16 + l15;
        int off = (row * 128 + kk * 64 + l4 * 16) ^ ((row & 7) << 4);
        af1[m][kk] = *reinterpret_cast<const bf16x8*>(Ab + off);
      }
    __builtin_amdgcn_s_setprio(1);
#pragma unroll
    for (int m = 0; m < 2; m++)
#pragma unroll
      for (int n = 0; n < 4; n++)
#pragma unroll
        for (int kk = 0; kk < 2; kk++)
          acc[2 + m][n] = __builtin_amdgcn_mfma_f32_16x16x32_bf16(
              af1[m][kk], bfr[n][kk], acc[2 + m][n], 0, 0, 0);
    __builtin_amdgcn_s_setprio(0);
  }

#pragma unroll
  for (int m = 0; m < 4; m++)
#pragma unroll
    for (int n = 0; n < 4; n++)
#pragma unroll
      for (int j = 0; j < 4; j++) {
        int row = m0 + wr * 64 + m * 16 + l4 * 4 + j;
        int col = n0 + wc * 64 + n * 16 + l15;
        Cg[(size_t)row * ldc + col] = (OT)acc[m][n][j];
      }
}

// ---------------- fused flash attention, T15 att[2] pipeline ----------------
// 512 threads (8 waves x 32 q-rows), grid (bh=32, sq=8) -> 1 block/CU.
// Body(it): barrier -> stage(it+2) -> QK^T(it+1)->scB [MFMA pipe] overlapping
// softmax(scA)+pack [VALU/trans] -> PV(it). Slot lifetime: tile t K read in
// body(t-1), V in body(t); slot (t+2)%3==(t-1)%3 frees at body(t)'s barrier.
__global__ __launch_bounds__(512, 2) void attn_fwd(
    const bf16* __restrict__ Q, const bf16* __restrict__ Kb,
    const bf16* __restrict__ Vt, bf16* __restrict__ O) {
  extern __shared__ char ash[];
  const int t = threadIdx.x, w = t >> 6, lane = t & 63;
  const int l31 = lane & 31, half = lane >> 5;
  const int bh = blockIdx.x;
  const int b = bh >> 4, h = bh & 15;
  const int sq0 = blockIdx.y * 256 + w * 32;
  const size_t hoff = (size_t)h * 128;
  const size_t bO = (size_t)b * 2048 + hoff;

  bf16x8 qf[8];
  {
    const bf16* qp = Q + ((size_t)(sq0 + l31) * 2 + b) * 2048 + hoff + half * 8;
#pragma unroll
    for (int dc = 0; dc < 8; dc++)
      qf[dc] = *reinterpret_cast<const bf16x8*>(qp + dc * 16);
  }

  const bf16* kp[2];
  const bf16* vp[2];
#pragma unroll
  for (int i = 0; i < 2; i++) {
    int s = i * 512 + t;
    int row = s >> 4, g = s & 15;
    int lg = g ^ (row & 15);
    kp[i] = Kb + ((size_t)row * 2 + b) * 2048 + hoff + lg * 8;  // + sk0*4096
    int d = row * 2 + (lg >> 3);
    vp[i] = Vt + (bO + d) * 2048 + (lg & 7) * 8;                // + sk0
  }

  auto stage = [&](int slot, int sk0) {
    char* Kd = ash + (size_t)slot * 32768;
    char* Vd = Kd + 16384;
#pragma unroll
    for (int i = 0; i < 2; i++)
      GLOAD16(kp[i] + (size_t)sk0 * 4096, Kd + (i * 512 + w * 64) * 16);
#pragma unroll
    for (int i = 0; i < 2; i++)
      GLOAD16(vp[i] + sk0, Vd + (i * 512 + w * 64) * 16);
  };

  auto loadK = [&](const char* ksb, bf16x8 (&dst)[4], int g) {
#pragma unroll
    for (int j = 0; j < 2; j++) {
      int dc = g * 2 + j;
      int kx = ((dc * 2 + half) ^ (l31 & 15)) << 4;
      dst[j * 2 + 0] = *reinterpret_cast<const bf16x8*>(ksb + (l31 << 8) + kx);
      dst[j * 2 + 1] =
          *reinterpret_cast<const bf16x8*>(ksb + ((32 + l31) << 8) + kx);
    }
  };

  f32x16 acc_o[4] = {};
  float m_run = -3e38f, l_run = 0.f;

  stage(0, 0);
  stage(1, 64);
  asm volatile("s_waitcnt vmcnt(4)" ::: "memory");
  __builtin_amdgcn_s_barrier();

  // prologue: QK^T(0) from slot 0
  f32x16 scA[2] = {};
  {
    const char* ksb = ash;
    bf16x8 ka[4], kb_[4], kc[4];
    auto mfmaK = [&](bf16x8 (&kf)[4], int g) {
#pragma unroll
      for (int j = 0; j < 2; j++) {
        scA[0] = __builtin_amdgcn_mfma_f32_32x32x16_bf16(
            kf[j * 2 + 0], qf[g * 2 + j], scA[0], 0, 0, 0);
        scA[1] = __builtin_amdgcn_mfma_f32_32x32x16_bf16(
            kf[j * 2 + 1], qf[g * 2 + j], scA[1], 0, 0, 0);
      }
    };
    loadK(ksb, ka, 0);
    loadK(ksb, kb_, 1);
    loadK(ksb, kc, 2);
    __builtin_amdgcn_s_setprio(1);
    mfmaK(ka, 0);
    loadK(ksb, ka, 3);
    mfmaK(kb_, 1);
    mfmaK(kc, 2);
    mfmaK(ka, 3);
    __builtin_amdgcn_s_setprio(0);
  }

  for (int it = 0; it < 32; ++it) {
    // tile it+1 landed (issued >= 1 full body ago -> cheap drain)
    asm volatile("s_waitcnt vmcnt(0)" ::: "memory");
    __builtin_amdgcn_s_barrier();   // + all waves past PV(it-1): slot (it+2)%3 free
    if (it + 2 < 32) stage((it + 2) % 3, (it + 2) * 64);

    // ---- QK^T(it+1) -> scB (MFMA pipe; overlaps softmax below) ----
    f32x16 scB[2] = {};
    if (it + 1 < 32) {
      const char* ksb = ash + (size_t)((it + 1) % 3) * 32768;
      bf16x8 ka[4], kb_[4], kc[4];
      auto mfmaK = [&](bf16x8 (&kf)[4], int g) {
#pragma unroll
        for (int j = 0; j < 2; j++) {
          scB[0] = __builtin_amdgcn_mfma_f32_32x32x16_bf16(
              kf[j * 2 + 0], qf[g * 2 + j], scB[0], 0, 0, 0);
          scB[1] = __builtin_amdgcn_mfma_f32_32x32x16_bf16(
              kf[j * 2 + 1], qf[g * 2 + j], scB[1], 0, 0, 0);
        }
      };
      loadK(ksb, ka, 0);
      loadK(ksb, kb_, 1);
      loadK(ksb, kc, 2);
      __builtin_amdgcn_s_setprio(1);
      mfmaK(ka, 0);
      loadK(ksb, ka, 3);
      mfmaK(kb_, 1);
      mfmaK(kc, 2);
      mfmaK(ka, 3);
      __builtin_amdgcn_s_setprio(0);
    }

    // ---- online softmax on scA (VALU/trans pipe) ----
    float red[8];
#pragma unroll
    for (int r = 0; r < 8; r++)
      red[r] = fmaxf(fmaxf(scA[0][r], scA[0][r + 8]),
                     fmaxf(scA[1][r], scA[1][r + 8]));
#pragma unroll
    for (int s = 4; s >= 1; s >>= 1)
#pragma unroll
      for (int r = 0; r < s; r++) red[r] = fmaxf(red[r], red[r + s]);
    float pmax = fmaxf(red[0], __shfl_xor(red[0], 32));

    if (!__all(pmax - m_run <= 11.0f)) {   // defer-max (T13)
      float mn = fmaxf(m_run, pmax);
      float f = exp2f(m_run - mn);
      m_run = mn;
      l_run *= f;
#pragma unroll
      for (int idx = 0; idx < 16; idx++) {
        float fr = __shfl(f, (idx & 3) + 8 * (idx >> 2) + half * 4);
#pragma unroll
        for (int dcb = 0; dcb < 4; dcb++) acc_o[dcb][idx] *= fr;
      }
    }

#pragma unroll
    for (int kt = 0; kt < 2; kt++)
#pragma unroll
      for (int r = 0; r < 16; r++) scA[kt][r] = exp2f(scA[kt][r] - m_run);
#pragma unroll
    for (int r = 0; r < 8; r++)
      red[r] = (scA[0][r] + scA[0][r + 8]) + (scA[1][r] + scA[1][r + 8]);
#pragma unroll
    for (int s = 4; s >= 1; s >>= 1)
#pragma unroll
      for (int r = 0; r < s; r++) red[r] += red[r + s];
    l_run += red[0] + __shfl_xor(red[0], 32);

    // ---- V prefetch from slot it%3 ----
    const char* vsb = ash + (size_t)(it % 3) * 32768 + 16384;
    bf16x8 va[4], vb[4], vc[4];
    auto loadV = [&](bf16x8 (&dst)[4], int dcb) {
      int rp = dcb * 16 + (l31 >> 1);
      int pbit = (l31 & 1) << 3;
#pragma unroll
      for (int skc = 0; skc < 4; skc++)
        dst[skc] = *reinterpret_cast<const bf16x8*>(
            vsb + (rp << 8) + (((pbit + skc * 2 + half) ^ (l31 >> 1)) << 4));
    };
    loadV(va, 0);
    loadV(vb, 1);
    loadV(vc, 2);

    // ---- P -> A-frags via permlane32_swap ----
    uint pa[4][4];
#pragma unroll
    for (int skc = 0; skc < 4; skc++) {
      int kt = skc >> 1, s8 = (skc & 1) * 8;
      uint pk01 = pack_bf16(scA[kt][s8 + 0], scA[kt][s8 + 1]);
      uint pk23 = pack_bf16(scA[kt][s8 + 2], scA[kt][s8 + 3]);
      uint pk45 = pack_bf16(scA[kt][s8 + 4], scA[kt][s8 + 5]);
      uint pk67 = pack_bf16(scA[kt][s8 + 6], scA[kt][s8 + 7]);
      uint2v r02 = __builtin_amdgcn_permlane32_swap(pk01, pk45, false, false);
      uint2v r13 = __builtin_amdgcn_permlane32_swap(pk23, pk67, false, false);
      pa[skc][0] = r02[0];
      pa[skc][1] = r13[0];
      pa[skc][2] = r02[1];
      pa[skc][3] = r13[1];
    }

    // ---- PV(it) with rolling prefetch ----
    auto mfmaV = [&](bf16x8 (&vf)[4], int dcb) {
#pragma unroll
      for (int skc = 0; skc < 4; skc++) {
        union { uint u[4]; bf16x8 v; } af;
        af.u[0] = pa[skc][0]; af.u[1] = pa[skc][1];
        af.u[2] = pa[skc][2]; af.u[3] = pa[skc][3];
        acc_o[dcb] = __builtin_amdgcn_mfma_f32_32x32x16_bf16(
            af.v, vf[skc], acc_o[dcb], 0, 0, 0);
      }
    };
    __builtin_amdgcn_s_setprio(1);
    mfmaV(va, 0);
    loadV(va, 3);
    mfmaV(vb, 1);
    mfmaV(vc, 2);
    mfmaV(va, 3);
    __builtin_amdgcn_s_setprio(0);

    scA[0] = scB[0];
    scA[1] = scB[1];
  }

  float inv = 1.0f / l_run;
#pragma unroll
  for (int idx = 0; idx < 16; idx++) {
    int sr = (idx & 3) + 8 * (idx >> 2) + half * 4;
    float invr = __shfl(inv, sr);
    bf16* op = O + ((size_t)(sq0 + sr) * 2 + b) * 2048 + hoff + l31;
#pragma unroll
    for (int dcb = 0; dcb < 4; dcb++)
      op[dcb * 32] = (bf16)(acc_o[dcb][idx] * invr);
  }
}

extern "C" void kernel_launch(void* const* d_in, const int* in_sizes, int n_in,
                              void* d_out, int out_size, void* d_ws,
                              size_t ws_size, hipStream_t stream) {
  (void)in_sizes; (void)n_in; (void)out_size; (void)ws_size;
  const float* x  = (const float*)d_in[0];
  const float* wq = (const float*)d_in[1];
  const float* wk = (const float*)d_in[2];
  const float* wv = (const float*)d_in[3];
  const float* wo = (const float*)d_in[4];
  float* out = (float*)d_out;
  char* ws = (char*)d_ws;
  bf16* xb   = (bf16*)(ws);
  bf16* qb   = (bf16*)(ws + (1u << 24));
  bf16* kb   = (bf16*)(ws + (2u << 24));
  bf16* vt   = (bf16*)(ws + (3u << 24));
  bf16* wb   = (bf16*)(ws + (4u << 24));
  bf16* wqk  = vt;
  bf16* attn = xb;
  const float SCALE = 0.08838834764831845f * 1.4426950408889634f;
  const int SMEM = 3 * 49152;
  const int SMEM_QK = 2 * 65536;
  const int SMEM_A = 3 * 32768;
  const long CSPLIT = (long)(kb - qb) - 2048;

  hipFuncSetAttribute((const void*)gemm_nt_256sq<bf16>,
                      hipFuncAttributeMaxDynamicSharedMemorySize, SMEM_QK);
  hipFuncSetAttribute((const void*)gemm_nt_256<bf16>,
                      hipFuncAttributeMaxDynamicSharedMemorySize, SMEM);
  hipFuncSetAttribute((const void*)gemm_nt_256<float>,
                      hipFuncAttributeMaxDynamicSharedMemorySize, SMEM);
  hipFuncSetAttribute((const void*)attn_fwd,
                      hipFuncAttributeMaxDynamicSharedMemorySize, SMEM_A);

  cast4<<<10240, 256, 0, stream>>>(x, wq, wk, wv, xb, wqk, wb, SCALE);

  dim3 gqk(16, 16, 1);
  gemm_nt_256sq<bf16><<<gqk, 512, SMEM_QK, stream>>>(xb, wqk, qb, 2048, 2048,
                                                     2048, 2048, CSPLIT);

  dim3 g2(16, 8, 2);
  gemm_nt_256<bf16><<<g2, 512, SMEM, stream>>>(wb, xb, vt, 2048, 2048, 4096, 2048,
                                               2048L, 4194304L, 0);

  dim3 ga(32, 8);
  attn_fwd<<<ga, 512, SMEM_A, stream>>>(qb, kb, vt, attn);

  cast_f32_to_bf16<<<2048, 256, 0, stream>>>(wo, wb, 4194304 / 8, 1.0f);
  dim3 g1(16, 16, 1);
  gemm_nt_256<float><<<g1, 512, SMEM, stream>>>(attn, wb, out, 2048, 2048, 2048,
                                                2048, 0, 0, 0);
}

// Round 17
// 244.464 us; speedup vs baseline: 1.0034x; 1.0034x over previous
//
#include <hip/hip_runtime.h>

typedef __bf16 bf16;
typedef __bf16 bf16x8 __attribute__((ext_vector_type(8)));
typedef float f32x4 __attribute__((ext_vector_type(4)));
typedef float f32x16 __attribute__((ext_vector_type(16)));
typedef unsigned int uint;
typedef uint uint2v __attribute__((ext_vector_type(2)));

#define GLOAD16(g, l)                                                        \
  __builtin_amdgcn_global_load_lds(                                          \
      (const __attribute__((address_space(1))) void*)(g),                    \
      (__attribute__((address_space(3))) void*)(l), 16, 0, 0)

__device__ inline uint pack_bf16(float a, float b) {
  union { bf16 h[2]; uint u; } x;
  x.h[0] = (bf16)a; x.h[1] = (bf16)b;
  return x.u;
}

// ---------------- casts ----------------
__global__ void cast_f32_to_bf16(const float* __restrict__ in,
                                 bf16* __restrict__ out, int n8, float scale) {
  int i = blockIdx.x * blockDim.x + threadIdx.x;
  if (i >= n8) return;
  const float4* p = reinterpret_cast<const float4*>(in) + (size_t)i * 2;
  float4 a = p[0], b = p[1];
  bf16x8 o;
  o[0] = (bf16)(a.x * scale); o[1] = (bf16)(a.y * scale);
  o[2] = (bf16)(a.z * scale); o[3] = (bf16)(a.w * scale);
  o[4] = (bf16)(b.x * scale); o[5] = (bf16)(b.y * scale);
  o[6] = (bf16)(b.z * scale); o[7] = (bf16)(b.w * scale);
  *reinterpret_cast<bf16x8*>(out + (size_t)i * 8) = o;
}

__global__ void cast4(const float* __restrict__ x, const float* __restrict__ wq,
                      const float* __restrict__ wk, const float* __restrict__ wv,
                      bf16* __restrict__ xb, bf16* __restrict__ wqk,
                      bf16* __restrict__ wvb, float qscale) {
  int i = blockIdx.x * blockDim.x + threadIdx.x;
  const float* src;
  bf16* dst;
  float s = 1.0f;
  int j;
  if (i < 1048576) {
    src = x; dst = xb; j = i;
  } else {
    int k = i - 1048576;
    int r = k >> 19;
    j = k & 524287;
    src = r == 0 ? wq : r == 1 ? wk : wv;
    dst = r == 0 ? wqk : r == 1 ? wqk + 4194304 : wvb;
    s = r == 0 ? qscale : 1.0f;
  }
  const float4* p = reinterpret_cast<const float4*>(src) + (size_t)j * 2;
  float4 a = p[0], b = p[1];
  bf16x8 o;
  o[0] = (bf16)(a.x * s); o[1] = (bf16)(a.y * s);
  o[2] = (bf16)(a.z * s); o[3] = (bf16)(a.w * s);
  o[4] = (bf16)(b.x * s); o[5] = (bf16)(b.y * s);
  o[6] = (bf16)(b.z * s); o[7] = (bf16)(b.w * s);
  *reinterpret_cast<bf16x8*>(dst + (size_t)j * 8) = o;
}

// ---------------- 256x256 deep-pipelined NT GEMM (QK projection) ------------
template <typename OT>
__global__ __launch_bounds__(512, 1) void gemm_nt_256sq(
    const bf16* __restrict__ A, const bf16* __restrict__ B, OT* __restrict__ C,
    int K, int lda, int ldb, int ldc, long cSplit) {
  extern __shared__ char sh[];
  const int t = threadIdx.x;
  const int w = t >> 6, lane = t & 63;
  const int l15 = lane & 15, l4 = lane >> 4;
  const int wr = w >> 2, wc = w & 3;
  const int gx = gridDim.x, gy = gridDim.y;
  const int nwg = gx * gy;
  const int bid = blockIdx.y * gx + blockIdx.x;
  const int fid = (bid & 7) * (nwg >> 3) + (bid >> 3);
  const int by = fid / gx, bx = fid - by * gx;
  const int m0 = by * 256, n0 = bx * 256;
  OT* Cg = C + ((n0 & 2048) ? cSplit : 0);

  int sRow[4], sCol[4];
#pragma unroll
  for (int i = 0; i < 4; i++) {
    int sB_ = (i * 512 + t) * 16;
    int row = sB_ >> 7;
    int ge = (sB_ ^ ((row & 7) << 4)) >> 1;
    sRow[i] = ge >> 6;
    sCol[i] = ge & 63;
  }

  const int NT = K >> 6;
  f32x4 acc[8][4] = {};

  auto stage = [&](int tt) {
    char* dst = sh + (size_t)(tt & 1) * 65536;
    const int k0 = tt * 64;
#pragma unroll
    for (int i = 0; i < 4; i++)
      GLOAD16(A + (size_t)(m0 + sRow[i]) * lda + k0 + sCol[i],
              dst + (i * 512 + w * 64) * 16);
#pragma unroll
    for (int i = 0; i < 4; i++)
      GLOAD16(B + (size_t)(n0 + sRow[i]) * ldb + k0 + sCol[i],
              dst + 32768 + (i * 512 + w * 64) * 16);
  };

  stage(0);
  for (int tt = 0; tt < NT; ++tt) {
    asm volatile("s_waitcnt vmcnt(0)" ::: "memory");
    __builtin_amdgcn_s_barrier();

    const char* Ab = sh + (size_t)(tt & 1) * 65536;
    const char* Bb = Ab + 32768;
    bf16x8 bfr[4][2];
#pragma unroll
    for (int n = 0; n < 4; n++)
#pragma unroll
      for (int kk = 0; kk < 2; kk++) {
        int row = wc * 64 + n * 16 + l15;
        int off = (row * 128 + kk * 64 + l4 * 16) ^ ((row & 7) << 4);
        bfr[n][kk] = *reinterpret_cast<const bf16x8*>(Bb + off);
      }
#pragma unroll
    for (int mp = 0; mp < 4; mp++) {
      bf16x8 af[2][2];
#pragma unroll
      for (int m = 0; m < 2; m++)
#pragma unroll
        for (int kk = 0; kk < 2; kk++) {
          int row = wr * 128 + (mp * 2 + m) * 16 + l15;
          int off = (row * 128 + kk * 64 + l4 * 16) ^ ((row & 7) << 4);
          af[m][kk] = *reinterpret_cast<const bf16x8*>(Ab + off);
        }
      __builtin_amdgcn_s_setprio(1);
#pragma unroll
      for (int m = 0; m < 2; m++)
#pragma unroll
        for (int n = 0; n < 4; n++)
#pragma unroll
          for (int kk = 0; kk < 2; kk++)
            acc[mp * 2 + m][n] = __builtin_amdgcn_mfma_f32_16x16x32_bf16(
                af[m][kk], bfr[n][kk], acc[mp * 2 + m][n], 0, 0, 0);
      __builtin_amdgcn_s_setprio(0);
      if (mp == 0 && tt + 1 < NT) stage(tt + 1);
    }
  }

#pragma unroll
  for (int m = 0; m < 8; m++)
#pragma unroll
    for (int n = 0; n < 4; n++)
#pragma unroll
      for (int j = 0; j < 4; j++) {
        int row = m0 + wr * 128 + m * 16 + l4 * 4 + j;
        int col = n0 + wc * 64 + n * 16 + l15;
        Cg[(size_t)row * ldc + col] = (OT)acc[m][n][j];
      }
}

// ---------------- 256x128 deep-pipelined NT GEMM (V, O-proj) ----------------
template <typename OT>
__global__ __launch_bounds__(512, 2) void gemm_nt_256(
    const bf16* __restrict__ A, const bf16* __restrict__ B, OT* __restrict__ C,
    int K, int lda, int ldb, int ldc, long bsB, long bsC, long cSplit) {
  extern __shared__ char sh[];
  const int t = threadIdx.x;
  const int w = t >> 6, lane = t & 63;
  const int l15 = lane & 15, l4 = lane >> 4;
  const int wr = w >> 1, wc = w & 1;
  const int gx = gridDim.x, gy = gridDim.y;
  const int nwg = gx * gy;
  const int bid = blockIdx.y * gx + blockIdx.x;
  const int fid = (bid & 7) * (nwg >> 3) + (bid >> 3);
  const int by = fid / gx, bx = fid - by * gx;
  const int m0 = by * 256;
  const int n0 = bx * 128;
  const bf16* Bg = B + (size_t)blockIdx.z * bsB;
  OT* Cg = C + (size_t)blockIdx.z * bsC + ((n0 & 2048) ? cSplit : 0);

  int sRow[4], sCol[4];
#pragma unroll
  for (int i = 0; i < 4; i++) {
    int sB_ = (i * 512 + t) * 16;
    int row = sB_ >> 7;
    int ge = (sB_ ^ ((row & 7) << 4)) >> 1;
    sRow[i] = ge >> 6;
    sCol[i] = ge & 63;
  }

  const int NT = K >> 6;
  f32x4 acc[4][4] = {};

  auto stage = [&](int tt) {
    char* dst = sh + (size_t)(tt % 3) * 49152;
    const int k0 = tt * 64;
#pragma unroll
    for (int i = 0; i < 4; i++)
      GLOAD16(A + (size_t)(m0 + sRow[i]) * lda + k0 + sCol[i],
              dst + (i * 512 + w * 64) * 16);
#pragma unroll
    for (int i = 0; i < 2; i++)
      GLOAD16(Bg + (size_t)(n0 + sRow[i]) * ldb + k0 + sCol[i],
              dst + 32768 + (i * 512 + w * 64) * 16);
  };

  stage(0);
  stage(1);
  for (int tt = 0; tt < NT; ++tt) {
    if (tt < NT - 1)
      asm volatile("s_waitcnt vmcnt(6)" ::: "memory");
    else
      asm volatile("s_waitcnt vmcnt(0)" ::: "memory");
    __builtin_amdgcn_s_barrier();

    const char* Ab = sh + (size_t)(tt % 3) * 49152;
    const char* Bb = Ab + 32768;
    bf16x8 bfr[4][2];
#pragma unroll
    for (int n = 0; n < 4; n++)
#pragma unroll
      for (int kk = 0; kk < 2; kk++) {
        int row = wc * 64 + n * 16 + l15;
        int off = (row * 128 + kk * 64 + l4 * 16) ^ ((row & 7) << 4);
        bfr[n][kk] = *reinterpret_cast<const bf16x8*>(Bb + off);
      }
    bf16x8 af0[2][2];
#pragma unroll
    for (int m = 0; m < 2; m++)
#pragma unroll
      for (int kk = 0; kk < 2; kk++) {
        int row = wr * 64 + m * 16 + l15;
        int off = (row * 128 + kk * 64 + l4 * 16) ^ ((row & 7) << 4);
        af0[m][kk] = *reinterpret_cast<const bf16x8*>(Ab + off);
      }
    __builtin_amdgcn_s_setprio(1);
#pragma unroll
    for (int m = 0; m < 2; m++)
#pragma unroll
      for (int n = 0; n < 4; n++)
#pragma unroll
        for (int kk = 0; kk < 2; kk++)
          acc[m][n] = __builtin_amdgcn_mfma_f32_16x16x32_bf16(
              af0[m][kk], bfr[n][kk], acc[m][n], 0, 0, 0);
    __builtin_amdgcn_s_setprio(0);

    if (tt + 2 < NT) stage(tt + 2);

    bf16x8 af1[2][2];
#pragma unroll
    for (int m = 0; m < 2; m++)
#pragma unroll
      for (int kk = 0; kk < 2; kk++) {
        int row = wr * 64 + (2 + m) * 16 + l15;
        int off = (row * 128 + kk * 64 + l4 * 16) ^ ((row & 7) << 4);
        af1[m][kk] = *reinterpret_cast<const bf16x8*>(Ab + off);
      }
    __builtin_amdgcn_s_setprio(1);
#pragma unroll
    for (int m = 0; m < 2; m++)
#pragma unroll
      for (int n = 0; n < 4; n++)
#pragma unroll
        for (int kk = 0; kk < 2; kk++)
          acc[2 + m][n] = __builtin_amdgcn_mfma_f32_16x16x32_bf16(
              af1[m][kk], bfr[n][kk], acc[2 + m][n], 0, 0, 0);
    __builtin_amdgcn_s_setprio(0);
  }

#pragma unroll
  for (int m = 0; m < 4; m++)
#pragma unroll
    for (int n = 0; n < 4; n++)
#pragma unroll
      for (int j = 0; j < 4; j++) {
        int row = m0 + wr * 64 + m * 16 + l4 * 4 + j;
        int col = n0 + wc * 64 + n * 16 + l15;
        Cg[(size_t)row * ldc + col] = (OT)acc[m][n][j];
      }
}

// ---------------- fused flash attention (r10/r15 form, honest VGPR budget) --
// 512 threads (8 waves x 32 q-rows), grid (bh=32, sq=8) -> 1 block/CU.
// Occupancy is LDS-pinned at 8 waves/CU for any VGPR count <= 256, so
// __launch_bounds__(512,1) lets the allocator hoist the 32 iter-invariant
// swizzled LDS addresses and deepen ds_read lookahead without spilling
// against a 128-reg target (r5's failure mode).
__global__ __launch_bounds__(512, 1) void attn_fwd(
    const bf16* __restrict__ Q, const bf16* __restrict__ Kb,
    const bf16* __restrict__ Vt, bf16* __restrict__ O) {
  extern __shared__ char ash[];
  const int t = threadIdx.x, w = t >> 6, lane = t & 63;
  const int l31 = lane & 31, half = lane >> 5;
  const int bh = blockIdx.x;
  const int b = bh >> 4, h = bh & 15;
  const int sq0 = blockIdx.y * 256 + w * 32;
  const size_t hoff = (size_t)h * 128;
  const size_t bO = (size_t)b * 2048 + hoff;

  bf16x8 qf[8];
  {
    const bf16* qp = Q + ((size_t)(sq0 + l31) * 2 + b) * 2048 + hoff + half * 8;
#pragma unroll
    for (int dc = 0; dc < 8; dc++)
      qf[dc] = *reinterpret_cast<const bf16x8*>(qp + dc * 16);
  }

  const bf16* kp[2];
  const bf16* vp[2];
#pragma unroll
  for (int i = 0; i < 2; i++) {
    int s = i * 512 + t;
    int row = s >> 4, g = s & 15;
    int lg = g ^ (row & 15);
    kp[i] = Kb + ((size_t)row * 2 + b) * 2048 + hoff + lg * 8;  // + sk0*4096
    int d = row * 2 + (lg >> 3);
    vp[i] = Vt + (bO + d) * 2048 + (lg & 7) * 8;                // + sk0
  }

  auto stage = [&](int slot, int sk0) {
    char* Kd = ash + (size_t)slot * 32768;
    char* Vd = Kd + 16384;
#pragma unroll
    for (int i = 0; i < 2; i++)
      GLOAD16(kp[i] + (size_t)sk0 * 4096, Kd + (i * 512 + w * 64) * 16);
#pragma unroll
    for (int i = 0; i < 2; i++)
      GLOAD16(vp[i] + sk0, Vd + (i * 512 + w * 64) * 16);
  };

  f32x16 acc_o[4] = {};
  float m_run = -3e38f, l_run = 0.f;

  stage(0, 0);
  stage(1, 64);

  for (int it = 0; it < 32; ++it) {
    if (it < 31)
      asm volatile("s_waitcnt vmcnt(4)" ::: "memory");
    else
      asm volatile("s_waitcnt vmcnt(0)" ::: "memory");
    __builtin_amdgcn_s_barrier();

    const char* ksb = ash + (size_t)(it % 3) * 32768;
    const char* vsb = ksb + 16384;

    f32x16 sc[2] = {};
    bf16x8 ka[4], kb_[4], kc[4];
    auto loadK = [&](bf16x8 (&dst)[4], int g) {
#pragma unroll
      for (int j = 0; j < 2; j++) {
        int dc = g * 2 + j;
        int kx = ((dc * 2 + half) ^ (l31 & 15)) << 4;
        dst[j * 2 + 0] = *reinterpret_cast<const bf16x8*>(ksb + (l31 << 8) + kx);
        dst[j * 2 + 1] =
            *reinterpret_cast<const bf16x8*>(ksb + ((32 + l31) << 8) + kx);
      }
    };
    auto mfmaK = [&](bf16x8 (&kf)[4], int g) {
#pragma unroll
      for (int j = 0; j < 2; j++) {
        sc[0] = __builtin_amdgcn_mfma_f32_32x32x16_bf16(kf[j * 2 + 0],
                                                        qf[g * 2 + j], sc[0], 0, 0, 0);
        sc[1] = __builtin_amdgcn_mfma_f32_32x32x16_bf16(kf[j * 2 + 1],
                                                        qf[g * 2 + j], sc[1], 0, 0, 0);
      }
    };
    loadK(ka, 0);
    loadK(kb_, 1);
    loadK(kc, 2);
    __builtin_amdgcn_s_setprio(1);
    mfmaK(ka, 0);
    loadK(ka, 3);
    mfmaK(kb_, 1);
    mfmaK(kc, 2);
    mfmaK(ka, 3);
    __builtin_amdgcn_s_setprio(0);

    if (it + 2 < 32) stage((it + 2) % 3, (it + 2) * 64);

    float red[8];
#pragma unroll
    for (int r = 0; r < 8; r++)
      red[r] = fmaxf(fmaxf(sc[0][r], sc[0][r + 8]),
                     fmaxf(sc[1][r], sc[1][r + 8]));
#pragma unroll
    for (int s = 4; s >= 1; s >>= 1)
#pragma unroll
      for (int r = 0; r < s; r++) red[r] = fmaxf(red[r], red[r + s]);
    float pmax = fmaxf(red[0], __shfl_xor(red[0], 32));

    if (!__all(pmax - m_run <= 11.0f)) {   // defer-max (T13)
      float mn = fmaxf(m_run, pmax);
      float f = exp2f(m_run - mn);
      m_run = mn;
      l_run *= f;
#pragma unroll
      for (int idx = 0; idx < 16; idx++) {
        float fr = __shfl(f, (idx & 3) + 8 * (idx >> 2) + half * 4);
#pragma unroll
        for (int dcb = 0; dcb < 4; dcb++) acc_o[dcb][idx] *= fr;
      }
    }

#pragma unroll
    for (int kt = 0; kt < 2; kt++)
#pragma unroll
      for (int r = 0; r < 16; r++) sc[kt][r] = exp2f(sc[kt][r] - m_run);
#pragma unroll
    for (int r = 0; r < 8; r++)
      red[r] = (sc[0][r] + sc[0][r + 8]) + (sc[1][r] + sc[1][r + 8]);
#pragma unroll
    for (int s = 4; s >= 1; s >>= 1)
#pragma unroll
      for (int r = 0; r < s; r++) red[r] += red[r + s];
    l_run += red[0] + __shfl_xor(red[0], 32);

    bf16x8 va[4], vb[4], vc[4];
    auto loadV = [&](bf16x8 (&dst)[4], int dcb) {
      int rp = dcb * 16 + (l31 >> 1);
      int pbit = (l31 & 1) << 3;
#pragma unroll
      for (int skc = 0; skc < 4; skc++)
        dst[skc] = *reinterpret_cast<const bf16x8*>(
            vsb + (rp << 8) + (((pbit + skc * 2 + half) ^ (l31 >> 1)) << 4));
    };
    loadV(va, 0);
    loadV(vb, 1);
    loadV(vc, 2);

    uint pa[4][4];
#pragma unroll
    for (int skc = 0; skc < 4; skc++) {
      int kt = skc >> 1, s8 = (skc & 1) * 8;
      uint pk01 = pack_bf16(sc[kt][s8 + 0], sc[kt][s8 + 1]);
      uint pk23 = pack_bf16(sc[kt][s8 + 2], sc[kt][s8 + 3]);
      uint pk45 = pack_bf16(sc[kt][s8 + 4], sc[kt][s8 + 5]);
      uint pk67 = pack_bf16(sc[kt][s8 + 6], sc[kt][s8 + 7]);
      uint2v r02 = __builtin_amdgcn_permlane32_swap(pk01, pk45, false, false);
      uint2v r13 = __builtin_amdgcn_permlane32_swap(pk23, pk67, false, false);
      pa[skc][0] = r02[0];
      pa[skc][1] = r13[0];
      pa[skc][2] = r02[1];
      pa[skc][3] = r13[1];
    }

    auto mfmaV = [&](bf16x8 (&vf)[4], int dcb) {
#pragma unroll
      for (int skc = 0; skc < 4; skc++) {
        union { uint u[4]; bf16x8 v; } af;
        af.u[0] = pa[skc][0]; af.u[1] = pa[skc][1];
        af.u[2] = pa[skc][2]; af.u[3] = pa[skc][3];
        acc_o[dcb] = __builtin_amdgcn_mfma_f32_32x32x16_bf16(
            af.v, vf[skc], acc_o[dcb], 0, 0, 0);
      }
    };
    __builtin_amdgcn_s_setprio(1);
    mfmaV(va, 0);
    loadV(va, 3);
    mfmaV(vb, 1);
    mfmaV(vc, 2);
    mfmaV(va, 3);
    __builtin_amdgcn_s_setprio(0);
  }

  float inv = 1.0f / l_run;
#pragma unroll
  for (int idx = 0; idx < 16; idx++) {
    int sr = (idx & 3) + 8 * (idx >> 2) + half * 4;
    float invr = __shfl(inv, sr);
    bf16* op = O + ((size_t)(sq0 + sr) * 2 + b) * 2048 + hoff + l31;
#pragma unroll
    for (int dcb = 0; dcb < 4; dcb++)
      op[dcb * 32] = (bf16)(acc_o[dcb][idx] * invr);
  }
}

extern "C" void kernel_launch(void* const* d_in, const int* in_sizes, int n_in,
                              void* d_out, int out_size, void* d_ws,
                              size_t ws_size, hipStream_t stream) {
  (void)in_sizes; (void)n_in; (void)out_size; (void)ws_size;
  const float* x  = (const float*)d_in[0];
  const float* wq = (const float*)d_in[1];
  const float* wk = (const float*)d_in[2];
  const float* wv = (const float*)d_in[3];
  const float* wo = (const float*)d_in[4];
  float* out = (float*)d_out;
  char* ws = (char*)d_ws;
  bf16* xb   = (bf16*)(ws);
  bf16* qb   = (bf16*)(ws + (1u << 24));
  bf16* kb   = (bf16*)(ws + (2u << 24));
  bf16* vt   = (bf16*)(ws + (3u << 24));
  bf16* wb   = (bf16*)(ws + (4u << 24));
  bf16* wqk  = vt;
  bf16* attn = xb;
  const float SCALE = 0.08838834764831845f * 1.4426950408889634f;
  const int SMEM = 3 * 49152;
  const int SMEM_QK = 2 * 65536;
  const int SMEM_A = 3 * 32768;
  const long CSPLIT = (long)(kb - qb) - 2048;

  hipFuncSetAttribute((const void*)gemm_nt_256sq<bf16>,
                      hipFuncAttributeMaxDynamicSharedMemorySize, SMEM_QK);
  hipFuncSetAttribute((const void*)gemm_nt_256<bf16>,
                      hipFuncAttributeMaxDynamicSharedMemorySize, SMEM);
  hipFuncSetAttribute((const void*)gemm_nt_256<float>,
                      hipFuncAttributeMaxDynamicSharedMemorySize, SMEM);
  hipFuncSetAttribute((const void*)attn_fwd,
                      hipFuncAttributeMaxDynamicSharedMemorySize, SMEM_A);

  cast4<<<10240, 256, 0, stream>>>(x, wq, wk, wv, xb, wqk, wb, SCALE);

  dim3 gqk(16, 16, 1);
  gemm_nt_256sq<bf16><<<gqk, 512, SMEM_QK, stream>>>(xb, wqk, qb, 2048, 2048,
                                                     2048, 2048, CSPLIT);

  dim3 g2(16, 8, 2);
  gemm_nt_256<bf16><<<g2, 512, SMEM, stream>>>(wb, xb, vt, 2048, 2048, 4096, 2048,
                                               2048L, 4194304L, 0);

  dim3 ga(32, 8);
  attn_fwd<<<ga, 512, SMEM_A, stream>>>(qb, kb, vt, attn);

  cast_f32_to_bf16<<<2048, 256, 0, stream>>>(wo, wb, 4194304 / 8, 1.0f);
  dim3 g1(16, 16, 1);
  gemm_nt_256<float><<<g1, 512, SMEM, stream>>>(attn, wb, out, 2048, 2048, 2048,
                                                2048, 0, 0, 0);
}